// Round 8
// baseline (59.647 us; speedup 1.0000x reference)
//
#include <hip/hip_runtime.h>

// ItemCode: PQ-coded embedding reconstruction.
//   input_ids : (256, 512) int32
//   item_codes: (1000000, 8) int32
//   centroids : (8, 256, 64) float32   (row 0 of each subspace is all-zero)
//   out       : (256, 512, 512) float32
//
// Round-8: split into (1) a prepass that resolves all (token,m) -> centroid
// f4-row offsets into d_ws (separates the random item_codes gather traffic
// temporally from the write stream), and (2) a near-pure write-stream kernel:
// linear 4 MB offset read + L2-resident centroid reads + 268 MB contiguous
// NT stores. Theory: removing random HBM reads from under the write stream
// recovers the ~20% gap to fillBuffer's pure-write bandwidth.
// Pad tokens (id==0) route to code 0, whose centroid row is all-zero.

#define VALS_ 256
#define NTOK_ (256 * 512)
#define TOKS_BLK 32               // 8 per wave
#define THREADS 256
#define ITERS 16                  // f4-stores per lane

typedef float f4 __attribute__((ext_vector_type(4)));
typedef int   i4 __attribute__((ext_vector_type(4)));

// ---- prepass: one thread per token; resolve 8 offsets ----
__global__ __launch_bounds__(THREADS) void ItemCode_prepass(
    const int* __restrict__ input_ids,
    const int* __restrict__ item_codes,
    int* __restrict__ ws_off)
{
    const int t  = blockIdx.x * THREADS + threadIdx.x;   // token, < 131072
    const int id = input_ids[t];
    const i4* row = reinterpret_cast<const i4*>(item_codes + (size_t)id * 8);
    i4 c0 = __builtin_nontemporal_load(&row[0]);         // 32 B aligned random line
    i4 c1 = __builtin_nontemporal_load(&row[1]);

    i4 o0, o1;
    #pragma unroll
    for (int j = 0; j < 4; ++j) {
        int cj = min(c0[j], VALS_ - 1); cj = id ? cj : 0;
        o0[j] = ((j << 8) + cj) << 4;
        int ck = min(c1[j], VALS_ - 1); ck = id ? ck : 0;
        o1[j] = (((j + 4) << 8) + ck) << 4;
    }
    i4* dst = reinterpret_cast<i4*>(ws_off + (size_t)t * 8);
    dst[0] = o0;
    dst[1] = o1;
}

// ---- stream: near-pure write kernel (linear offset read, L2 centroid read) ----
__global__ __launch_bounds__(THREADS) void ItemCode_stream(
    const int* __restrict__ ws_off,
    const float* __restrict__ centroids,
    float* __restrict__ out)
{
    const int tid  = threadIdx.x;
    const int wave = tid >> 6;
    const int lane = tid & 63;
    const int tok0w = blockIdx.x * TOKS_BLK + wave * 8;   // this wave's 8 tokens

    // one coalesced 256 B load: lane l = slot (token l>>3, m l&7)
    const int off = ws_off[tok0w * 8 + lane];

    const f4* __restrict__ cent4 = reinterpret_cast<const f4*>(centroids);
    f4* __restrict__ out4 = reinterpret_cast<f4*>(out);
    const int ob = tok0w * 128 + lane;    // wave writes 16 KB contiguous
    const int s4 = lane & 15;

    int ci[ITERS];
    #pragma unroll
    for (int it = 0; it < ITERS; ++it) {
        // flat f4 index within wave region: t_local = it>>1 ; m = (it&1)*4 + (lane>>4)
        const int owner = ((it >> 1) << 3) | ((it & 1) << 2) | (lane >> 4);
        ci[it] = __shfl(off, owner) + s4;
    }

    f4 v[ITERS];
    #pragma unroll
    for (int it = 0; it < ITERS; ++it)
        v[it] = cent4[ci[it]];            // L2-resident (512 KB table)

    #pragma unroll
    for (int it = 0; it < ITERS; ++it)
        __builtin_nontemporal_store(v[it], &out4[ob + it * 64]);
}

// ---- fallback (round-7 fused kernel) if ws is too small ----
__global__ __launch_bounds__(THREADS) void ItemCode_fused(
    const int* __restrict__ input_ids,
    const int* __restrict__ item_codes,
    const float* __restrict__ centroids,
    float* __restrict__ out)
{
    const int tid  = threadIdx.x;
    const int wave = tid >> 6;
    const int lane = tid & 63;
    const int tok0w = blockIdx.x * TOKS_BLK + wave * 8;

    const int id = input_ids[tok0w + (lane >> 3)];
    int code = __builtin_nontemporal_load(&item_codes[(size_t)id * 8 + (lane & 7)]);
    code = min(code, VALS_ - 1);
    code = id ? code : 0;
    const int off = (((lane & 7) << 8) + code) << 4;

    const f4* __restrict__ cent4 = reinterpret_cast<const f4*>(centroids);
    f4* __restrict__ out4 = reinterpret_cast<f4*>(out);
    const int ob = tok0w * 128 + lane;
    const int s4 = lane & 15;

    int ci[ITERS];
    #pragma unroll
    for (int it = 0; it < ITERS; ++it) {
        const int owner = ((it >> 1) << 3) | ((it & 1) << 2) | (lane >> 4);
        ci[it] = __shfl(off, owner) + s4;
    }
    f4 v[ITERS];
    #pragma unroll
    for (int it = 0; it < ITERS; ++it)
        v[it] = cent4[ci[it]];
    #pragma unroll
    for (int it = 0; it < ITERS; ++it)
        __builtin_nontemporal_store(v[it], &out4[ob + it * 64]);
}

extern "C" void kernel_launch(void* const* d_in, const int* in_sizes, int n_in,
                              void* d_out, int out_size, void* d_ws, size_t ws_size,
                              hipStream_t stream) {
    const int*   input_ids  = (const int*)d_in[0];
    const int*   item_codes = (const int*)d_in[1];
    const float* centroids  = (const float*)d_in[2];
    float*       out        = (float*)d_out;

    const size_t ws_needed = (size_t)NTOK_ * 8 * sizeof(int);   // 4 MiB
    if (ws_size >= ws_needed) {
        int* ws_off = (int*)d_ws;
        ItemCode_prepass<<<NTOK_ / THREADS, THREADS, 0, stream>>>(input_ids, item_codes, ws_off);
        ItemCode_stream<<<NTOK_ / TOKS_BLK, THREADS, 0, stream>>>(ws_off, centroids, out);
    } else {
        ItemCode_fused<<<NTOK_ / TOKS_BLK, THREADS, 0, stream>>>(input_ids, item_codes, centroids, out);
    }
}